// Round 1
// baseline (1639.532 us; speedup 1.0000x reference)
//
#include <hip/hip_runtime.h>
#include <hip/hip_bf16.h>

// Problem constants (fixed by the reference)
#define D 128            // feature dim (in = hid = out = 128)
#define N_HEDGES 10000

// ---------------------------------------------------------------------------
// CSR build: counts -> exclusive scan (+ 1/deg) -> fill adjacency lists
// ---------------------------------------------------------------------------

__global__ void count_k(const int* __restrict__ row, const int* __restrict__ col,
                        int* __restrict__ cnt_n, int* __restrict__ cnt_e, int nnz) {
    int i = blockIdx.x * blockDim.x + threadIdx.x;
    if (i < nnz) {
        atomicAdd(&cnt_n[row[i]], 1);
        atomicAdd(&cnt_e[col[i]], 1);
    }
}

// single-block exclusive scan over n counts; also writes inv[i] = cnt>0 ? 1/cnt : 0
__global__ __launch_bounds__(1024) void scan_k(const int* __restrict__ cnt,
                                               int* __restrict__ off,
                                               float* __restrict__ inv, int n) {
    __shared__ int lsum[1024];
    int t = threadIdx.x;
    int chunk = (n + 1023) >> 10;
    int lo = t * chunk;
    int hi = min(lo + chunk, n);
    int s = 0;
    for (int i = lo; i < hi; ++i) s += cnt[i];
    lsum[t] = s;
    __syncthreads();
    // Hillis-Steele inclusive scan over 1024 partials
    for (int d = 1; d < 1024; d <<= 1) {
        int v = (t >= d) ? lsum[t - d] : 0;
        __syncthreads();
        lsum[t] += v;
        __syncthreads();
    }
    int run = (t == 0) ? 0 : lsum[t - 1];   // exclusive base for this chunk
    for (int i = lo; i < hi; ++i) {
        int c = cnt[i];
        off[i] = run;
        inv[i] = (c > 0) ? (1.0f / (float)c) : 0.0f;
        run += c;
    }
    if (t == 1023) off[n] = run;            // its chunk is past n -> run == total
}

__global__ void fill_k(const int* __restrict__ row, const int* __restrict__ col,
                       const int* __restrict__ off_n, const int* __restrict__ off_e,
                       int* __restrict__ cur_n, int* __restrict__ cur_e,
                       int* __restrict__ list_n, int* __restrict__ list_e, int nnz) {
    int i = blockIdx.x * blockDim.x + threadIdx.x;
    if (i < nnz) {
        int r = row[i], c = col[i];
        int pn = atomicAdd(&cur_n[r], 1);
        list_n[off_n[r] + pn] = c;
        int pe = atomicAdd(&cur_e[c], 1);
        list_e[off_e[c] + pe] = r;
    }
}

// ---------------------------------------------------------------------------
// fp32 GEMM: Y[M,128] = X[M,128] @ W[128,128]
// block = 256 threads, 32-row tile; W staged fully in LDS (64KB), x tile 16KB.
// thread t: col-pair cp = t&63 -> cols {2cp,2cp+1}; row group rg = t>>6 (8 rows)
// ---------------------------------------------------------------------------
__global__ __launch_bounds__(256) void gemm128(const float* __restrict__ X,
                                               const float* __restrict__ W,
                                               float* __restrict__ Y, int M) {
    __shared__ float Wl[D * D];       // 64 KB
    __shared__ float Xl[32 * D];      // 16 KB
    int t = threadIdx.x;
    int block_row = blockIdx.x * 32;

    // stage W: 16384 floats = 4096 float4
    const float4* W4 = (const float4*)W;
    float4* Wl4 = (float4*)Wl;
#pragma unroll
    for (int i = 0; i < 16; ++i) Wl4[t + 256 * i] = W4[t + 256 * i];

    // stage X tile: 4096 floats = 1024 float4 (row = idx>>5, col4 = idx&31)
    int rows = M - block_row; if (rows > 32) rows = 32;
#pragma unroll
    for (int i = 0; i < 4; ++i) {
        int idx = t + 256 * i;
        int r = idx >> 5, c4 = idx & 31;
        float4 v = make_float4(0.f, 0.f, 0.f, 0.f);
        if (r < rows) v = ((const float4*)(X + (size_t)(block_row + r) * D))[c4];
        ((float4*)Xl)[idx] = v;
    }
    __syncthreads();

    int cp = t & 63;
    int rg = t >> 6;                  // 0..3, 8 rows each
    float2 acc[8];
#pragma unroll
    for (int r = 0; r < 8; ++r) acc[r] = make_float2(0.f, 0.f);

    const float* xbase = Xl + (rg * 8) * D;
#pragma unroll
    for (int k4 = 0; k4 < 32; ++k4) {
        float4 xv[8];
#pragma unroll
        for (int r = 0; r < 8; ++r) xv[r] = ((const float4*)(xbase + r * D))[k4];
        float2 wv[4];
#pragma unroll
        for (int j = 0; j < 4; ++j) wv[j] = ((const float2*)(Wl + (k4 * 4 + j) * D))[cp];
#pragma unroll
        for (int r = 0; r < 8; ++r) {
            acc[r].x += xv[r].x * wv[0].x; acc[r].y += xv[r].x * wv[0].y;
            acc[r].x += xv[r].y * wv[1].x; acc[r].y += xv[r].y * wv[1].y;
            acc[r].x += xv[r].z * wv[2].x; acc[r].y += xv[r].z * wv[2].y;
            acc[r].x += xv[r].w * wv[3].x; acc[r].y += xv[r].w * wv[3].y;
        }
    }
#pragma unroll
    for (int r = 0; r < 8; ++r) {
        int row = block_row + rg * 8 + r;
        if (row < M) ((float2*)(Y + (size_t)row * D))[cp] = acc[r];
    }
}

// ---------------------------------------------------------------------------
// Segmented gather-sum, one wave (64 lanes) per segment, float2 per lane.
//   edge_agg: m[e] = b_inv[e] * sum_{i in e} xw[i]
//   node_agg: out[n] = d_inv[n] * sum_{e ni n} m[e] + bias  (optional relu)
// ---------------------------------------------------------------------------
__global__ __launch_bounds__(256) void edge_agg(const float* __restrict__ src,
                                                const int* __restrict__ offs,
                                                const int* __restrict__ list,
                                                const float* __restrict__ inv,
                                                float* __restrict__ dst, int nseg) {
    int w = (blockIdx.x * 256 + threadIdx.x) >> 6;
    int lane = threadIdx.x & 63;
    if (w >= nseg) return;
    int s = offs[w], e = offs[w + 1];
    float2 acc = make_float2(0.f, 0.f);
    for (int i = s; i < e; ++i) {
        float2 v = ((const float2*)(src + (size_t)list[i] * D))[lane];
        acc.x += v.x; acc.y += v.y;
    }
    float sc = inv[w];
    ((float2*)(dst + (size_t)w * D))[lane] = make_float2(acc.x * sc, acc.y * sc);
}

template <bool RELU>
__global__ __launch_bounds__(256) void node_agg(const float* __restrict__ src,
                                                const int* __restrict__ offs,
                                                const int* __restrict__ list,
                                                const float* __restrict__ inv,
                                                const float* __restrict__ bias,
                                                float* __restrict__ dst, int nseg) {
    int w = (blockIdx.x * 256 + threadIdx.x) >> 6;
    int lane = threadIdx.x & 63;
    if (w >= nseg) return;
    int s = offs[w], e = offs[w + 1];
    float2 acc = make_float2(0.f, 0.f);
    for (int i = s; i < e; ++i) {
        float2 v = ((const float2*)(src + (size_t)list[i] * D))[lane];
        acc.x += v.x; acc.y += v.y;
    }
    float sc = inv[w];
    float2 bv = ((const float2*)bias)[lane];
    float ox = acc.x * sc + bv.x;
    float oy = acc.y * sc + bv.y;
    if (RELU) { ox = fmaxf(ox, 0.f); oy = fmaxf(oy, 0.f); }
    ((float2*)(dst + (size_t)w * D))[lane] = make_float2(ox, oy);
}

// ---------------------------------------------------------------------------
// Launch
// ---------------------------------------------------------------------------
extern "C" void kernel_launch(void* const* d_in, const int* in_sizes, int n_in,
                              void* d_out, int out_size, void* d_ws, size_t ws_size,
                              hipStream_t stream) {
    const float* x  = (const float*)d_in[0];
    const int*   ei = (const int*)d_in[1];
    const float* W1 = (const float*)d_in[2];
    const float* b1 = (const float*)d_in[3];
    const float* W2 = (const float*)d_in[4];
    const float* b2 = (const float*)d_in[5];
    float* out = (float*)d_out;

    const int NNZ = in_sizes[1] / 2;
    const int N   = in_sizes[0] / D;       // 50000 nodes
    const int E   = N_HEDGES;              // 10000 hyperedges

    const int* row = ei;                   // node index per incidence
    const int* col = ei + NNZ;             // hyperedge index per incidence

    // workspace carve-up (256B aligned chunks)
    char* p = (char*)d_ws;
    auto alloc = [&](size_t bytes) {
        char* r = p;
        p += (bytes + 255) & ~(size_t)255;
        return r;
    };
    float* xw    = (float*)alloc(sizeof(float) * (size_t)N * D);  // 25.6 MB
    float* m     = (float*)alloc(sizeof(float) * (size_t)E * D);  // 5.12 MB
    int*   off_e = (int*)alloc(sizeof(int) * (E + 1));
    int*   off_n = (int*)alloc(sizeof(int) * (N + 1));
    float* b_inv = (float*)alloc(sizeof(float) * E);
    float* d_inv = (float*)alloc(sizeof(float) * N);
    char*  zstart = p;                                            // zero region start
    int*   cnt_e = (int*)alloc(sizeof(int) * E);
    int*   cnt_n = (int*)alloc(sizeof(int) * N);
    int*   cur_e = (int*)alloc(sizeof(int) * E);
    int*   cur_n = (int*)alloc(sizeof(int) * N);
    size_t zbytes = (size_t)(p - zstart);
    int*   list_e = (int*)alloc(sizeof(int) * (size_t)NNZ);
    int*   list_n = (int*)alloc(sizeof(int) * (size_t)NNZ);

    hipMemsetAsync(zstart, 0, zbytes, stream);

    int nnz_blocks = (NNZ + 255) / 256;
    count_k<<<nnz_blocks, 256, 0, stream>>>(row, col, cnt_n, cnt_e, NNZ);
    scan_k<<<1, 1024, 0, stream>>>(cnt_e, off_e, b_inv, E);
    scan_k<<<1, 1024, 0, stream>>>(cnt_n, off_n, d_inv, N);
    fill_k<<<nnz_blocks, 256, 0, stream>>>(row, col, off_n, off_e,
                                           cur_n, cur_e, list_n, list_e, NNZ);

    int gemm_blocks = (N + 31) / 32;
    int eblk = (E + 3) / 4;   // 4 waves per block
    int nblk = (N + 3) / 4;

    // ---- layer 1: h = relu(hconv(x, W1, b1)); h lives in d_out ----
    gemm128<<<gemm_blocks, 256, 0, stream>>>(x, W1, xw, N);
    edge_agg<<<eblk, 256, 0, stream>>>(xw, off_e, list_e, b_inv, m, E);
    node_agg<true><<<nblk, 256, 0, stream>>>(m, off_n, list_n, d_inv, b1, out, N);

    // ---- layer 2: out = hconv(h, W2, b2) ----
    gemm128<<<gemm_blocks, 256, 0, stream>>>(out, W2, xw, N);
    edge_agg<<<eblk, 256, 0, stream>>>(xw, off_e, list_e, b_inv, m, E);
    node_agg<false><<<nblk, 256, 0, stream>>>(m, off_n, list_n, d_inv, b2, out, N);
}

// Round 2
// 692.424 us; speedup vs baseline: 2.3678x; 2.3678x over previous
//
#include <hip/hip_runtime.h>
#include <hip/hip_bf16.h>

// Problem constants (fixed by the reference)
#define D 128            // feature dim (in = hid = out = 128)
#define N_HEDGES 10000

// ---------------------------------------------------------------------------
// CSR build: counts -> exclusive scan (+ 1/deg) -> fill adjacency lists
// ---------------------------------------------------------------------------

__global__ void count_k(const int* __restrict__ row, const int* __restrict__ col,
                        int* __restrict__ cnt_n, int* __restrict__ cnt_e, int nnz) {
    int i = blockIdx.x * blockDim.x + threadIdx.x;
    if (i < nnz) {
        atomicAdd(&cnt_n[row[i]], 1);
        atomicAdd(&cnt_e[col[i]], 1);
    }
}

// single-block exclusive scan over n counts; also writes inv[i] = cnt>0 ? 1/cnt : 0
__global__ __launch_bounds__(1024) void scan_k(const int* __restrict__ cnt,
                                               int* __restrict__ off,
                                               float* __restrict__ inv, int n) {
    __shared__ int lsum[1024];
    int t = threadIdx.x;
    int chunk = (n + 1023) >> 10;
    int lo = t * chunk;
    int hi = min(lo + chunk, n);
    int s = 0;
    for (int i = lo; i < hi; ++i) s += cnt[i];
    lsum[t] = s;
    __syncthreads();
    // Hillis-Steele inclusive scan over 1024 partials
    for (int d = 1; d < 1024; d <<= 1) {
        int v = (t >= d) ? lsum[t - d] : 0;
        __syncthreads();
        lsum[t] += v;
        __syncthreads();
    }
    int run = (t == 0) ? 0 : lsum[t - 1];   // exclusive base for this chunk
    for (int i = lo; i < hi; ++i) {
        int c = cnt[i];
        off[i] = run;
        inv[i] = (c > 0) ? (1.0f / (float)c) : 0.0f;
        run += c;
    }
    if (t == 1023) off[n] = run;            // its chunk is past n -> run == total
}

__global__ void fill_k(const int* __restrict__ row, const int* __restrict__ col,
                       const int* __restrict__ off_n, const int* __restrict__ off_e,
                       int* __restrict__ cur_n, int* __restrict__ cur_e,
                       int* __restrict__ list_n, int* __restrict__ list_e, int nnz) {
    int i = blockIdx.x * blockDim.x + threadIdx.x;
    if (i < nnz) {
        int r = row[i], c = col[i];
        int pn = atomicAdd(&cur_n[r], 1);
        list_n[off_n[r] + pn] = c;
        int pe = atomicAdd(&cur_e[c], 1);
        list_e[off_e[c] + pe] = r;
    }
}

// ---------------------------------------------------------------------------
// fp32 GEMM: Y[M,128] = X[M,128] @ W[128,128]
// block = 256 threads, 32-row tile; W staged fully in LDS (64KB), x tile 16KB.
// thread t: col-pair cp = t&63 -> cols {2cp,2cp+1}; row group rg = t>>6 (8 rows)
// NOTE: k4 loop must NOT be fully unrolled — round-1 profile showed full unroll
// hoisted 1024 regs of LDS reads -> spill -> 1.06 GB scratch writes, 580 us.
// ---------------------------------------------------------------------------
__global__ __launch_bounds__(256, 2) void gemm128(const float* __restrict__ X,
                                                  const float* __restrict__ W,
                                                  float* __restrict__ Y, int M) {
    __shared__ float Wl[D * D];       // 64 KB
    __shared__ float Xl[32 * D];      // 16 KB
    int t = threadIdx.x;
    int block_row = blockIdx.x * 32;

    // stage W: 16384 floats = 4096 float4
    const float4* W4 = (const float4*)W;
    float4* Wl4 = (float4*)Wl;
#pragma unroll
    for (int i = 0; i < 16; ++i) Wl4[t + 256 * i] = W4[t + 256 * i];

    // stage X tile: 4096 floats = 1024 float4 (row = idx>>5, col4 = idx&31)
    int rows = M - block_row; if (rows > 32) rows = 32;
#pragma unroll
    for (int i = 0; i < 4; ++i) {
        int idx = t + 256 * i;
        int r = idx >> 5, c4 = idx & 31;
        float4 v = make_float4(0.f, 0.f, 0.f, 0.f);
        if (r < rows) v = ((const float4*)(X + (size_t)(block_row + r) * D))[c4];
        ((float4*)Xl)[idx] = v;
    }
    __syncthreads();

    int cp = t & 63;
    int rg = t >> 6;                  // 0..3, 8 rows each
    float2 acc[8];
#pragma unroll
    for (int r = 0; r < 8; ++r) acc[r] = make_float2(0.f, 0.f);

    const float* xbase = Xl + (rg * 8) * D;
#pragma unroll 2
    for (int k4 = 0; k4 < 32; ++k4) {
        float2 wv0 = ((const float2*)(Wl + (k4 * 4 + 0) * D))[cp];
        float2 wv1 = ((const float2*)(Wl + (k4 * 4 + 1) * D))[cp];
        float2 wv2 = ((const float2*)(Wl + (k4 * 4 + 2) * D))[cp];
        float2 wv3 = ((const float2*)(Wl + (k4 * 4 + 3) * D))[cp];
#pragma unroll
        for (int r = 0; r < 8; ++r) {
            float4 xv = ((const float4*)(xbase + r * D))[k4];
            acc[r].x += xv.x * wv0.x; acc[r].y += xv.x * wv0.y;
            acc[r].x += xv.y * wv1.x; acc[r].y += xv.y * wv1.y;
            acc[r].x += xv.z * wv2.x; acc[r].y += xv.z * wv2.y;
            acc[r].x += xv.w * wv3.x; acc[r].y += xv.w * wv3.y;
        }
    }
#pragma unroll
    for (int r = 0; r < 8; ++r) {
        int row = block_row + rg * 8 + r;
        if (row < M) ((float2*)(Y + (size_t)row * D))[cp] = acc[r];
    }
}

// ---------------------------------------------------------------------------
// Segmented gather-sum, one wave (64 lanes) per segment, float2 per lane.
//   edge_agg: m[e] = b_inv[e] * sum_{i in e} xw[i]
//   node_agg: out[n] = d_inv[n] * sum_{e ni n} m[e] + bias  (optional relu)
// ---------------------------------------------------------------------------
__global__ __launch_bounds__(256) void edge_agg(const float* __restrict__ src,
                                                const int* __restrict__ offs,
                                                const int* __restrict__ list,
                                                const float* __restrict__ inv,
                                                float* __restrict__ dst, int nseg) {
    int w = (blockIdx.x * 256 + threadIdx.x) >> 6;
    int lane = threadIdx.x & 63;
    if (w >= nseg) return;
    int s = offs[w], e = offs[w + 1];
    float2 acc = make_float2(0.f, 0.f);
    for (int i = s; i < e; ++i) {
        float2 v = ((const float2*)(src + (size_t)list[i] * D))[lane];
        acc.x += v.x; acc.y += v.y;
    }
    float sc = inv[w];
    ((float2*)(dst + (size_t)w * D))[lane] = make_float2(acc.x * sc, acc.y * sc);
}

template <bool RELU>
__global__ __launch_bounds__(256) void node_agg(const float* __restrict__ src,
                                                const int* __restrict__ offs,
                                                const int* __restrict__ list,
                                                const float* __restrict__ inv,
                                                const float* __restrict__ bias,
                                                float* __restrict__ dst, int nseg) {
    int w = (blockIdx.x * 256 + threadIdx.x) >> 6;
    int lane = threadIdx.x & 63;
    if (w >= nseg) return;
    int s = offs[w], e = offs[w + 1];
    float2 acc = make_float2(0.f, 0.f);
    for (int i = s; i < e; ++i) {
        float2 v = ((const float2*)(src + (size_t)list[i] * D))[lane];
        acc.x += v.x; acc.y += v.y;
    }
    float sc = inv[w];
    float2 bv = ((const float2*)bias)[lane];
    float ox = acc.x * sc + bv.x;
    float oy = acc.y * sc + bv.y;
    if (RELU) { ox = fmaxf(ox, 0.f); oy = fmaxf(oy, 0.f); }
    ((float2*)(dst + (size_t)w * D))[lane] = make_float2(ox, oy);
}

// ---------------------------------------------------------------------------
// Launch
// ---------------------------------------------------------------------------
extern "C" void kernel_launch(void* const* d_in, const int* in_sizes, int n_in,
                              void* d_out, int out_size, void* d_ws, size_t ws_size,
                              hipStream_t stream) {
    const float* x  = (const float*)d_in[0];
    const int*   ei = (const int*)d_in[1];
    const float* W1 = (const float*)d_in[2];
    const float* b1 = (const float*)d_in[3];
    const float* W2 = (const float*)d_in[4];
    const float* b2 = (const float*)d_in[5];
    float* out = (float*)d_out;

    const int NNZ = in_sizes[1] / 2;
    const int N   = in_sizes[0] / D;       // 50000 nodes
    const int E   = N_HEDGES;              // 10000 hyperedges

    const int* row = ei;                   // node index per incidence
    const int* col = ei + NNZ;             // hyperedge index per incidence

    // workspace carve-up (256B aligned chunks)
    char* p = (char*)d_ws;
    auto alloc = [&](size_t bytes) {
        char* r = p;
        p += (bytes + 255) & ~(size_t)255;
        return r;
    };
    float* xw    = (float*)alloc(sizeof(float) * (size_t)N * D);  // 25.6 MB
    float* m     = (float*)alloc(sizeof(float) * (size_t)E * D);  // 5.12 MB
    int*   off_e = (int*)alloc(sizeof(int) * (E + 1));
    int*   off_n = (int*)alloc(sizeof(int) * (N + 1));
    float* b_inv = (float*)alloc(sizeof(float) * E);
    float* d_inv = (float*)alloc(sizeof(float) * N);
    char*  zstart = p;                                            // zero region start
    int*   cnt_e = (int*)alloc(sizeof(int) * E);
    int*   cnt_n = (int*)alloc(sizeof(int) * N);
    int*   cur_e = (int*)alloc(sizeof(int) * E);
    int*   cur_n = (int*)alloc(sizeof(int) * N);
    size_t zbytes = (size_t)(p - zstart);
    int*   list_e = (int*)alloc(sizeof(int) * (size_t)NNZ);
    int*   list_n = (int*)alloc(sizeof(int) * (size_t)NNZ);

    hipMemsetAsync(zstart, 0, zbytes, stream);

    int nnz_blocks = (NNZ + 255) / 256;
    count_k<<<nnz_blocks, 256, 0, stream>>>(row, col, cnt_n, cnt_e, NNZ);
    scan_k<<<1, 1024, 0, stream>>>(cnt_e, off_e, b_inv, E);
    scan_k<<<1, 1024, 0, stream>>>(cnt_n, off_n, d_inv, N);
    fill_k<<<nnz_blocks, 256, 0, stream>>>(row, col, off_n, off_e,
                                           cur_n, cur_e, list_n, list_e, NNZ);

    int gemm_blocks = (N + 31) / 32;
    int eblk = (E + 3) / 4;   // 4 waves per block
    int nblk = (N + 3) / 4;

    // ---- layer 1: h = relu(hconv(x, W1, b1)); h lives in d_out ----
    gemm128<<<gemm_blocks, 256, 0, stream>>>(x, W1, xw, N);
    edge_agg<<<eblk, 256, 0, stream>>>(xw, off_e, list_e, b_inv, m, E);
    node_agg<true><<<nblk, 256, 0, stream>>>(m, off_n, list_n, d_inv, b1, out, N);

    // ---- layer 2: out = hconv(h, W2, b2) ----
    gemm128<<<gemm_blocks, 256, 0, stream>>>(out, W2, xw, N);
    edge_agg<<<eblk, 256, 0, stream>>>(xw, off_e, list_e, b_inv, m, E);
    node_agg<false><<<nblk, 256, 0, stream>>>(m, off_n, list_n, d_inv, b2, out, N);
}

// Round 3
// 598.933 us; speedup vs baseline: 2.7374x; 1.1561x over previous
//
#include <hip/hip_runtime.h>
#include <hip/hip_bf16.h>

// Problem constants (fixed by the reference)
#define D 128            // feature dim (in = hid = out = 128)
#define N_HEDGES 10000
#define SCAN_TILE 4096   // ints per block in the scan kernels (256 thr x 16)

// ---------------------------------------------------------------------------
// CSR build: counts -> 2-level scan (+ 1/deg) -> fill adjacency lists
// ---------------------------------------------------------------------------

__global__ void count_k(const int* __restrict__ row, const int* __restrict__ col,
                        int* __restrict__ cnt_n, int* __restrict__ cnt_e, int nnz) {
    int i = blockIdx.x * blockDim.x + threadIdx.x;
    if (i < nnz) {
        atomicAdd(&cnt_n[row[i]], 1);
        atomicAdd(&cnt_e[col[i]], 1);
    }
}

// Level 1: per-block sums. grid = ceil(n/SCAN_TILE), block = 256.
// Round-2 lesson: the old single-block scan was 110us (1 CU, latency-bound).
__global__ __launch_bounds__(256) void scan_partial(const int* __restrict__ cnt,
                                                    int* __restrict__ psum, int n) {
    __shared__ int red[256];
    int t = threadIdx.x;
    int base = blockIdx.x * SCAN_TILE + t * 16;
    int s = 0;
#pragma unroll
    for (int j = 0; j < 4; ++j) {
        int idx = base + j * 4;
        if (idx + 3 < n) {
            int4 v = *(const int4*)(cnt + idx);
            s += v.x + v.y + v.z + v.w;
        } else {
            for (int k = 0; k < 4; ++k)
                if (idx + k < n) s += cnt[idx + k];
        }
    }
    red[t] = s;
    __syncthreads();
    for (int d = 128; d > 0; d >>= 1) {
        if (t < d) red[t] += red[t + d];
        __syncthreads();
    }
    if (t == 0) psum[blockIdx.x] = red[0];
}

// Level 2: per-block exclusive scan + base from partials (nP <= 16, read
// redundantly by every block). Writes off[0..n] and inv[0..n).
__global__ __launch_bounds__(256) void scan_final(const int* __restrict__ cnt,
                                                  const int* __restrict__ psum, int nP,
                                                  int* __restrict__ off,
                                                  float* __restrict__ inv, int n) {
    __shared__ int lsum[256];
    int t = threadIdx.x;
    int b = blockIdx.x;

    // block base = sum of partials before this block (and total for off[n])
    int block_base = 0, total = 0;
    for (int j = 0; j < nP; ++j) {
        int v = psum[j];
        if (j < b) block_base += v;
        total += v;
    }
    if (b == 0 && t == 0) off[n] = total;

    // per-thread load of 16 ints + local exclusive scan
    int base = b * SCAN_TILE + t * 16;
    int c[16];
#pragma unroll
    for (int j = 0; j < 4; ++j) {
        int idx = base + j * 4;
        if (idx + 3 < n) {
            int4 v = *(const int4*)(cnt + idx);
            c[j * 4 + 0] = v.x; c[j * 4 + 1] = v.y; c[j * 4 + 2] = v.z; c[j * 4 + 3] = v.w;
        } else {
            for (int k = 0; k < 4; ++k)
                c[j * 4 + k] = (idx + k < n) ? cnt[idx + k] : 0;
        }
    }
    int tot = 0;
#pragma unroll
    for (int j = 0; j < 16; ++j) tot += c[j];

    // 256-wide Hillis-Steele inclusive scan of per-thread totals
    lsum[t] = tot;
    __syncthreads();
    for (int d = 1; d < 256; d <<= 1) {
        int v = (t >= d) ? lsum[t - d] : 0;
        __syncthreads();
        lsum[t] += v;
        __syncthreads();
    }
    int run = block_base + ((t == 0) ? 0 : lsum[t - 1]);

    int o[16];
    float iv[16];
#pragma unroll
    for (int j = 0; j < 16; ++j) {
        o[j] = run;
        iv[j] = (c[j] > 0) ? (1.0f / (float)c[j]) : 0.0f;
        run += c[j];
    }
#pragma unroll
    for (int j = 0; j < 4; ++j) {
        int idx = base + j * 4;
        if (idx + 3 < n) {
            *(int4*)(off + idx) = make_int4(o[j * 4], o[j * 4 + 1], o[j * 4 + 2], o[j * 4 + 3]);
            *(float4*)(inv + idx) = make_float4(iv[j * 4], iv[j * 4 + 1], iv[j * 4 + 2], iv[j * 4 + 3]);
        } else {
            for (int k = 0; k < 4; ++k)
                if (idx + k < n) { off[idx + k] = o[j * 4 + k]; inv[idx + k] = iv[j * 4 + k]; }
        }
    }
}

__global__ void fill_k(const int* __restrict__ row, const int* __restrict__ col,
                       const int* __restrict__ off_n, const int* __restrict__ off_e,
                       int* __restrict__ cur_n, int* __restrict__ cur_e,
                       int* __restrict__ list_n, int* __restrict__ list_e, int nnz) {
    int i = blockIdx.x * blockDim.x + threadIdx.x;
    if (i < nnz) {
        int r = row[i], c = col[i];
        int pn = atomicAdd(&cur_n[r], 1);
        list_n[off_n[r] + pn] = c;
        int pe = atomicAdd(&cur_e[c], 1);
        list_e[off_e[c] + pe] = r;
    }
}

// ---------------------------------------------------------------------------
// fp32 GEMM: Y[M,128] = X[M,128] @ W[128,128]
// block = 256 threads, 32-row tile; W staged fully in LDS (64KB), x tile 16KB.
// NOTE: k4 loop must NOT be fully unrolled — round-1 profile showed full unroll
// hoisted 1024 regs of LDS reads -> spill -> 1.06 GB scratch writes, 580 us.
// ---------------------------------------------------------------------------
__global__ __launch_bounds__(256, 2) void gemm128(const float* __restrict__ X,
                                                  const float* __restrict__ W,
                                                  float* __restrict__ Y, int M) {
    __shared__ float Wl[D * D];       // 64 KB
    __shared__ float Xl[32 * D];      // 16 KB
    int t = threadIdx.x;
    int block_row = blockIdx.x * 32;

    // stage W: 16384 floats = 4096 float4
    const float4* W4 = (const float4*)W;
    float4* Wl4 = (float4*)Wl;
#pragma unroll
    for (int i = 0; i < 16; ++i) Wl4[t + 256 * i] = W4[t + 256 * i];

    // stage X tile: 4096 floats = 1024 float4 (row = idx>>5, col4 = idx&31)
    int rows = M - block_row; if (rows > 32) rows = 32;
#pragma unroll
    for (int i = 0; i < 4; ++i) {
        int idx = t + 256 * i;
        int r = idx >> 5, c4 = idx & 31;
        float4 v = make_float4(0.f, 0.f, 0.f, 0.f);
        if (r < rows) v = ((const float4*)(X + (size_t)(block_row + r) * D))[c4];
        ((float4*)Xl)[idx] = v;
    }
    __syncthreads();

    int cp = t & 63;
    int rg = t >> 6;                  // 0..3, 8 rows each
    float2 acc[8];
#pragma unroll
    for (int r = 0; r < 8; ++r) acc[r] = make_float2(0.f, 0.f);

    const float* xbase = Xl + (rg * 8) * D;
#pragma unroll 2
    for (int k4 = 0; k4 < 32; ++k4) {
        float2 wv0 = ((const float2*)(Wl + (k4 * 4 + 0) * D))[cp];
        float2 wv1 = ((const float2*)(Wl + (k4 * 4 + 1) * D))[cp];
        float2 wv2 = ((const float2*)(Wl + (k4 * 4 + 2) * D))[cp];
        float2 wv3 = ((const float2*)(Wl + (k4 * 4 + 3) * D))[cp];
#pragma unroll
        for (int r = 0; r < 8; ++r) {
            float4 xv = ((const float4*)(xbase + r * D))[k4];
            acc[r].x += xv.x * wv0.x; acc[r].y += xv.x * wv0.y;
            acc[r].x += xv.y * wv1.x; acc[r].y += xv.y * wv1.y;
            acc[r].x += xv.z * wv2.x; acc[r].y += xv.z * wv2.y;
            acc[r].x += xv.w * wv3.x; acc[r].y += xv.w * wv3.y;
        }
    }
#pragma unroll
    for (int r = 0; r < 8; ++r) {
        int row = block_row + rg * 8 + r;
        if (row < M) ((float2*)(Y + (size_t)row * D))[cp] = acc[r];
    }
}

// ---------------------------------------------------------------------------
// Segmented gather-sum, one wave (64 lanes) per segment, float2 per lane.
// ---------------------------------------------------------------------------
__global__ __launch_bounds__(256) void edge_agg(const float* __restrict__ src,
                                                const int* __restrict__ offs,
                                                const int* __restrict__ list,
                                                const float* __restrict__ inv,
                                                float* __restrict__ dst, int nseg) {
    int w = (blockIdx.x * 256 + threadIdx.x) >> 6;
    int lane = threadIdx.x & 63;
    if (w >= nseg) return;
    int s = offs[w], e = offs[w + 1];
    float2 acc = make_float2(0.f, 0.f);
    for (int i = s; i < e; ++i) {
        float2 v = ((const float2*)(src + (size_t)list[i] * D))[lane];
        acc.x += v.x; acc.y += v.y;
    }
    float sc = inv[w];
    ((float2*)(dst + (size_t)w * D))[lane] = make_float2(acc.x * sc, acc.y * sc);
}

template <bool RELU>
__global__ __launch_bounds__(256) void node_agg(const float* __restrict__ src,
                                                const int* __restrict__ offs,
                                                const int* __restrict__ list,
                                                const float* __restrict__ inv,
                                                const float* __restrict__ bias,
                                                float* __restrict__ dst, int nseg) {
    int w = (blockIdx.x * 256 + threadIdx.x) >> 6;
    int lane = threadIdx.x & 63;
    if (w >= nseg) return;
    int s = offs[w], e = offs[w + 1];
    float2 acc = make_float2(0.f, 0.f);
    for (int i = s; i < e; ++i) {
        float2 v = ((const float2*)(src + (size_t)list[i] * D))[lane];
        acc.x += v.x; acc.y += v.y;
    }
    float sc = inv[w];
    float2 bv = ((const float2*)bias)[lane];
    float ox = acc.x * sc + bv.x;
    float oy = acc.y * sc + bv.y;
    if (RELU) { ox = fmaxf(ox, 0.f); oy = fmaxf(oy, 0.f); }
    ((float2*)(dst + (size_t)w * D))[lane] = make_float2(ox, oy);
}

// ---------------------------------------------------------------------------
// Launch
// ---------------------------------------------------------------------------
extern "C" void kernel_launch(void* const* d_in, const int* in_sizes, int n_in,
                              void* d_out, int out_size, void* d_ws, size_t ws_size,
                              hipStream_t stream) {
    const float* x  = (const float*)d_in[0];
    const int*   ei = (const int*)d_in[1];
    const float* W1 = (const float*)d_in[2];
    const float* b1 = (const float*)d_in[3];
    const float* W2 = (const float*)d_in[4];
    const float* b2 = (const float*)d_in[5];
    float* out = (float*)d_out;

    const int NNZ = in_sizes[1] / 2;
    const int N   = in_sizes[0] / D;       // 50000 nodes
    const int E   = N_HEDGES;              // 10000 hyperedges

    const int* row = ei;                   // node index per incidence
    const int* col = ei + NNZ;             // hyperedge index per incidence

    // workspace carve-up (256B aligned chunks)
    char* p = (char*)d_ws;
    auto alloc = [&](size_t bytes) {
        char* r = p;
        p += (bytes + 255) & ~(size_t)255;
        return r;
    };
    float* xw    = (float*)alloc(sizeof(float) * (size_t)N * D);  // 25.6 MB
    float* m     = (float*)alloc(sizeof(float) * (size_t)E * D);  // 5.12 MB
    int*   off_e = (int*)alloc(sizeof(int) * (E + 1));
    int*   off_n = (int*)alloc(sizeof(int) * (N + 1));
    float* b_inv = (float*)alloc(sizeof(float) * E);
    float* d_inv = (float*)alloc(sizeof(float) * N);
    int*   psum_e = (int*)alloc(sizeof(int) * 16);
    int*   psum_n = (int*)alloc(sizeof(int) * 16);
    char*  zstart = p;                                            // zero region start
    int*   cnt_e = (int*)alloc(sizeof(int) * E);
    int*   cnt_n = (int*)alloc(sizeof(int) * N);
    int*   cur_e = (int*)alloc(sizeof(int) * E);
    int*   cur_n = (int*)alloc(sizeof(int) * N);
    size_t zbytes = (size_t)(p - zstart);
    int*   list_e = (int*)alloc(sizeof(int) * (size_t)NNZ);
    int*   list_n = (int*)alloc(sizeof(int) * (size_t)NNZ);

    hipMemsetAsync(zstart, 0, zbytes, stream);

    int nnz_blocks = (NNZ + 255) / 256;
    int pE = (E + SCAN_TILE - 1) / SCAN_TILE;   // 3
    int pN = (N + SCAN_TILE - 1) / SCAN_TILE;   // 13

    count_k<<<nnz_blocks, 256, 0, stream>>>(row, col, cnt_n, cnt_e, NNZ);
    scan_partial<<<pE, 256, 0, stream>>>(cnt_e, psum_e, E);
    scan_partial<<<pN, 256, 0, stream>>>(cnt_n, psum_n, N);
    scan_final<<<pE, 256, 0, stream>>>(cnt_e, psum_e, pE, off_e, b_inv, E);
    scan_final<<<pN, 256, 0, stream>>>(cnt_n, psum_n, pN, off_n, d_inv, N);
    fill_k<<<nnz_blocks, 256, 0, stream>>>(row, col, off_n, off_e,
                                           cur_n, cur_e, list_n, list_e, NNZ);

    int gemm_blocks = (N + 31) / 32;
    int eblk = (E + 3) / 4;   // 4 waves per block
    int nblk = (N + 3) / 4;

    // ---- layer 1: h = relu(hconv(x, W1, b1)); h lives in d_out ----
    gemm128<<<gemm_blocks, 256, 0, stream>>>(x, W1, xw, N);
    edge_agg<<<eblk, 256, 0, stream>>>(xw, off_e, list_e, b_inv, m, E);
    node_agg<true><<<nblk, 256, 0, stream>>>(m, off_n, list_n, d_inv, b1, out, N);

    // ---- layer 2: out = hconv(h, W2, b2) ----
    gemm128<<<gemm_blocks, 256, 0, stream>>>(out, W2, xw, N);
    edge_agg<<<eblk, 256, 0, stream>>>(xw, off_e, list_e, b_inv, m, E);
    node_agg<false><<<nblk, 256, 0, stream>>>(m, off_n, list_n, d_inv, b2, out, N);
}

// Round 5
// 455.689 us; speedup vs baseline: 3.5979x; 1.3143x over previous
//
#include <hip/hip_runtime.h>
#include <hip/hip_bf16.h>

// Problem constants (fixed by the reference)
#define D 128            // feature dim (in = hid = out = 128)
#define N_HEDGES 10000
#define SCAN_TILE 4096   // ints per block in the scan kernels (256 thr x 16)

// ---------------------------------------------------------------------------
// CSR build: counts -> 2-level scan (+ 1/deg) -> fill adjacency lists
// Lists are ushort (node idx < 50000, edge idx < 10000 both fit) — halves the
// cross-XCD line-bounce traffic of the scattered fill (round-3: 84.8 MB writes).
// ---------------------------------------------------------------------------

__global__ void count_k(const int* __restrict__ row, const int* __restrict__ col,
                        int* __restrict__ cnt_n, int* __restrict__ cnt_e, int nnz) {
    int i = blockIdx.x * blockDim.x + threadIdx.x;
    if (i < nnz) {
        atomicAdd(&cnt_n[row[i]], 1);
        atomicAdd(&cnt_e[col[i]], 1);
    }
}

// Level 1: per-block sums. grid = ceil(n/SCAN_TILE), block = 256.
// Round-2 lesson: single-block scan was 110us (1 CU, latency-bound).
__global__ __launch_bounds__(256) void scan_partial(const int* __restrict__ cnt,
                                                    int* __restrict__ psum, int n) {
    __shared__ int red[256];
    int t = threadIdx.x;
    int base = blockIdx.x * SCAN_TILE + t * 16;
    int s = 0;
#pragma unroll
    for (int j = 0; j < 4; ++j) {
        int idx = base + j * 4;
        if (idx + 3 < n) {
            int4 v = *(const int4*)(cnt + idx);
            s += v.x + v.y + v.z + v.w;
        } else {
            for (int k = 0; k < 4; ++k)
                if (idx + k < n) s += cnt[idx + k];
        }
    }
    red[t] = s;
    __syncthreads();
    for (int d = 128; d > 0; d >>= 1) {
        if (t < d) red[t] += red[t + d];
        __syncthreads();
    }
    if (t == 0) psum[blockIdx.x] = red[0];
}

// Level 2: per-block exclusive scan + base from partials (nP <= 16, read
// redundantly by every block). Writes off[0..n] and inv[0..n).
__global__ __launch_bounds__(256) void scan_final(const int* __restrict__ cnt,
                                                  const int* __restrict__ psum, int nP,
                                                  int* __restrict__ off,
                                                  float* __restrict__ inv, int n) {
    __shared__ int lsum[256];
    int t = threadIdx.x;
    int b = blockIdx.x;

    int block_base = 0, total = 0;
    for (int j = 0; j < nP; ++j) {
        int v = psum[j];
        if (j < b) block_base += v;
        total += v;
    }
    if (b == 0 && t == 0) off[n] = total;

    int base = b * SCAN_TILE + t * 16;
    int c[16];
#pragma unroll
    for (int j = 0; j < 4; ++j) {
        int idx = base + j * 4;
        if (idx + 3 < n) {
            int4 v = *(const int4*)(cnt + idx);
            c[j * 4 + 0] = v.x; c[j * 4 + 1] = v.y; c[j * 4 + 2] = v.z; c[j * 4 + 3] = v.w;
        } else {
            for (int k = 0; k < 4; ++k)
                c[j * 4 + k] = (idx + k < n) ? cnt[idx + k] : 0;
        }
    }
    int tot = 0;
#pragma unroll
    for (int j = 0; j < 16; ++j) tot += c[j];

    lsum[t] = tot;
    __syncthreads();
    for (int d = 1; d < 256; d <<= 1) {
        int v = (t >= d) ? lsum[t - d] : 0;
        __syncthreads();
        lsum[t] += v;
        __syncthreads();
    }
    int run = block_base + ((t == 0) ? 0 : lsum[t - 1]);

    int o[16];
    float iv[16];
#pragma unroll
    for (int j = 0; j < 16; ++j) {
        o[j] = run;
        iv[j] = (c[j] > 0) ? (1.0f / (float)c[j]) : 0.0f;
        run += c[j];
    }
#pragma unroll
    for (int j = 0; j < 4; ++j) {
        int idx = base + j * 4;
        if (idx + 3 < n) {
            *(int4*)(off + idx) = make_int4(o[j * 4], o[j * 4 + 1], o[j * 4 + 2], o[j * 4 + 3]);
            *(float4*)(inv + idx) = make_float4(iv[j * 4], iv[j * 4 + 1], iv[j * 4 + 2], iv[j * 4 + 3]);
        } else {
            for (int k = 0; k < 4; ++k)
                if (idx + k < n) { off[idx + k] = o[j * 4 + k]; inv[idx + k] = iv[j * 4 + k]; }
        }
    }
}

__global__ void fill_k(const int* __restrict__ row, const int* __restrict__ col,
                       const int* __restrict__ off_n, const int* __restrict__ off_e,
                       int* __restrict__ cur_n, int* __restrict__ cur_e,
                       ushort* __restrict__ list_n, ushort* __restrict__ list_e, int nnz) {
    int i = blockIdx.x * blockDim.x + threadIdx.x;
    if (i < nnz) {
        int r = row[i], c = col[i];
        int pn = atomicAdd(&cur_n[r], 1);
        list_n[off_n[r] + pn] = (ushort)c;       // hyperedge idx < 10000
        int pe = atomicAdd(&cur_e[c], 1);
        list_e[off_e[c] + pe] = (ushort)r;       // node idx < 50000
    }
}

// ---------------------------------------------------------------------------
// fp32 GEMM: Y[M,128] = X[M,128] @ W[128,128]
// NOTE: k4 loop must NOT be fully unrolled — round-1 profile showed full unroll
// hoisted 1024 regs of LDS reads -> spill -> 1.06 GB scratch writes, 580 us.
// ---------------------------------------------------------------------------
__global__ __launch_bounds__(256, 2) void gemm128(const float* __restrict__ X,
                                                  const float* __restrict__ W,
                                                  float* __restrict__ Y, int M) {
    __shared__ float Wl[D * D];       // 64 KB
    __shared__ float Xl[32 * D];      // 16 KB
    int t = threadIdx.x;
    int block_row = blockIdx.x * 32;

    const float4* W4 = (const float4*)W;
    float4* Wl4 = (float4*)Wl;
#pragma unroll
    for (int i = 0; i < 16; ++i) Wl4[t + 256 * i] = W4[t + 256 * i];

    int rows = M - block_row; if (rows > 32) rows = 32;
#pragma unroll
    for (int i = 0; i < 4; ++i) {
        int idx = t + 256 * i;
        int r = idx >> 5, c4 = idx & 31;
        float4 v = make_float4(0.f, 0.f, 0.f, 0.f);
        if (r < rows) v = ((const float4*)(X + (size_t)(block_row + r) * D))[c4];
        ((float4*)Xl)[idx] = v;
    }
    __syncthreads();

    int cp = t & 63;
    int rg = t >> 6;                  // 0..3, 8 rows each
    float2 acc[8];
#pragma unroll
    for (int r = 0; r < 8; ++r) acc[r] = make_float2(0.f, 0.f);

    const float* xbase = Xl + (rg * 8) * D;
#pragma unroll 2
    for (int k4 = 0; k4 < 32; ++k4) {
        float2 wv0 = ((const float2*)(Wl + (k4 * 4 + 0) * D))[cp];
        float2 wv1 = ((const float2*)(Wl + (k4 * 4 + 1) * D))[cp];
        float2 wv2 = ((const float2*)(Wl + (k4 * 4 + 2) * D))[cp];
        float2 wv3 = ((const float2*)(Wl + (k4 * 4 + 3) * D))[cp];
#pragma unroll
        for (int r = 0; r < 8; ++r) {
            float4 xv = ((const float4*)(xbase + r * D))[k4];
            acc[r].x += xv.x * wv0.x; acc[r].y += xv.x * wv0.y;
            acc[r].x += xv.y * wv1.x; acc[r].y += xv.y * wv1.y;
            acc[r].x += xv.z * wv2.x; acc[r].y += xv.z * wv2.y;
            acc[r].x += xv.w * wv3.x; acc[r].y += xv.w * wv3.y;
        }
    }
#pragma unroll
    for (int r = 0; r < 8; ++r) {
        int row = block_row + rg * 8 + r;
        if (row < M) ((float2*)(Y + (size_t)row * D))[cp] = acc[r];
    }
}

// ---------------------------------------------------------------------------
// Segmented gather-sum, one wave per segment, 2 rows per iteration:
// lanes 0-31 take even incidences, lanes 32-63 odd; each half-wave reads a
// full 512B row as float4/lane. Halves trip count, doubles load width vs r3.
// ---------------------------------------------------------------------------
__global__ __launch_bounds__(256) void edge_agg(const float* __restrict__ src,
                                                const int* __restrict__ offs,
                                                const ushort* __restrict__ list,
                                                const float* __restrict__ inv,
                                                float* __restrict__ dst, int nseg) {
    int w = (blockIdx.x * 256 + threadIdx.x) >> 6;
    int lane = threadIdx.x & 63;
    if (w >= nseg) return;
    int s = offs[w], e = offs[w + 1];
    int half = lane >> 5;
    int c4 = lane & 31;
    float4 acc = make_float4(0.f, 0.f, 0.f, 0.f);
    int i = s;
#pragma unroll 2
    for (; i + 2 <= e; i += 2) {
        int r = list[i + half];
        float4 v = ((const float4*)(src + (size_t)r * D))[c4];
        acc.x += v.x; acc.y += v.y; acc.z += v.z; acc.w += v.w;
    }
    if (i < e && half == 0) {
        int r = list[i];
        float4 v = ((const float4*)(src + (size_t)r * D))[c4];
        acc.x += v.x; acc.y += v.y; acc.z += v.z; acc.w += v.w;
    }
    acc.x += __shfl_xor(acc.x, 32);
    acc.y += __shfl_xor(acc.y, 32);
    acc.z += __shfl_xor(acc.z, 32);
    acc.w += __shfl_xor(acc.w, 32);
    if (half == 0) {
        float sc = inv[w];
        ((float4*)(dst + (size_t)w * D))[c4] =
            make_float4(acc.x * sc, acc.y * sc, acc.z * sc, acc.w * sc);
    }
}

template <bool RELU>
__global__ __launch_bounds__(256) void node_agg(const float* __restrict__ src,
                                                const int* __restrict__ offs,
                                                const ushort* __restrict__ list,
                                                const float* __restrict__ inv,
                                                const float* __restrict__ bias,
                                                float* __restrict__ dst, int nseg) {
    int w = (blockIdx.x * 256 + threadIdx.x) >> 6;
    int lane = threadIdx.x & 63;
    if (w >= nseg) return;
    int s = offs[w], e = offs[w + 1];
    int half = lane >> 5;
    int c4 = lane & 31;
    float4 acc = make_float4(0.f, 0.f, 0.f, 0.f);
    int i = s;
#pragma unroll 2
    for (; i + 2 <= e; i += 2) {
        int r = list[i + half];
        float4 v = ((const float4*)(src + (size_t)r * D))[c4];
        acc.x += v.x; acc.y += v.y; acc.z += v.z; acc.w += v.w;
    }
    if (i < e && half == 0) {
        int r = list[i];
        float4 v = ((const float4*)(src + (size_t)r * D))[c4];
        acc.x += v.x; acc.y += v.y; acc.z += v.z; acc.w += v.w;
    }
    acc.x += __shfl_xor(acc.x, 32);
    acc.y += __shfl_xor(acc.y, 32);
    acc.z += __shfl_xor(acc.z, 32);
    acc.w += __shfl_xor(acc.w, 32);
    if (half == 0) {
        float sc = inv[w];
        float4 bv = ((const float4*)bias)[c4];
        float ox = acc.x * sc + bv.x;
        float oy = acc.y * sc + bv.y;
        float oz = acc.z * sc + bv.z;
        float ow = acc.w * sc + bv.w;
        if (RELU) {
            ox = fmaxf(ox, 0.f); oy = fmaxf(oy, 0.f);
            oz = fmaxf(oz, 0.f); ow = fmaxf(ow, 0.f);
        }
        ((float4*)(dst + (size_t)w * D))[c4] = make_float4(ox, oy, oz, ow);
    }
}

// ---------------------------------------------------------------------------
// Launch
// ---------------------------------------------------------------------------
extern "C" void kernel_launch(void* const* d_in, const int* in_sizes, int n_in,
                              void* d_out, int out_size, void* d_ws, size_t ws_size,
                              hipStream_t stream) {
    const float* x  = (const float*)d_in[0];
    const int*   ei = (const int*)d_in[1];
    const float* W1 = (const float*)d_in[2];
    const float* b1 = (const float*)d_in[3];
    const float* W2 = (const float*)d_in[4];
    const float* b2 = (const float*)d_in[5];
    float* out = (float*)d_out;

    const int NNZ = in_sizes[1] / 2;
    const int N   = in_sizes[0] / D;       // 50000 nodes
    const int E   = N_HEDGES;              // 10000 hyperedges

    const int* row = ei;                   // node index per incidence
    const int* col = ei + NNZ;             // hyperedge index per incidence

    char* p = (char*)d_ws;
    auto alloc = [&](size_t bytes) {
        char* r = p;
        p += (bytes + 255) & ~(size_t)255;
        return r;
    };
    float* xw    = (float*)alloc(sizeof(float) * (size_t)N * D);  // 25.6 MB
    float* m     = (float*)alloc(sizeof(float) * (size_t)E * D);  // 5.12 MB
    int*   off_e = (int*)alloc(sizeof(int) * (E + 1));
    int*   off_n = (int*)alloc(sizeof(int) * (N + 1));
    float* b_inv = (float*)alloc(sizeof(float) * E);
    float* d_inv = (float*)alloc(sizeof(float) * N);
    int*   psum_e = (int*)alloc(sizeof(int) * 16);
    int*   psum_n = (int*)alloc(sizeof(int) * 16);
    char*  zstart = p;                                            // zero region start
    int*   cnt_e = (int*)alloc(sizeof(int) * E);
    int*   cnt_n = (int*)alloc(sizeof(int) * N);
    int*   cur_e = (int*)alloc(sizeof(int) * E);
    int*   cur_n = (int*)alloc(sizeof(int) * N);
    size_t zbytes = (size_t)(p - zstart);
    ushort* list_e = (ushort*)alloc(sizeof(ushort) * (size_t)NNZ);
    ushort* list_n = (ushort*)alloc(sizeof(ushort) * (size_t)NNZ);

    hipMemsetAsync(zstart, 0, zbytes, stream);

    int nnz_blocks = (NNZ + 255) / 256;
    int pE = (E + SCAN_TILE - 1) / SCAN_TILE;   // 3
    int pN = (N + SCAN_TILE - 1) / SCAN_TILE;   // 13

    count_k<<<nnz_blocks, 256, 0, stream>>>(row, col, cnt_n, cnt_e, NNZ);
    scan_partial<<<pE, 256, 0, stream>>>(cnt_e, psum_e, E);
    scan_partial<<<pN, 256, 0, stream>>>(cnt_n, psum_n, N);
    scan_final<<<pE, 256, 0, stream>>>(cnt_e, psum_e, pE, off_e, b_inv, E);
    scan_final<<<pN, 256, 0, stream>>>(cnt_n, psum_n, pN, off_n, d_inv, N);
    fill_k<<<nnz_blocks, 256, 0, stream>>>(row, col, off_n, off_e,
                                           cur_n, cur_e, list_n, list_e, NNZ);

    int gemm_blocks = (N + 31) / 32;
    int eblk = (E + 3) / 4;   // 4 waves per block
    int nblk = (N + 3) / 4;

    // ---- layer 1: h = relu(hconv(x, W1, b1)); h lives in d_out ----
    gemm128<<<gemm_blocks, 256, 0, stream>>>(x, W1, xw, N);
    edge_agg<<<eblk, 256, 0, stream>>>(xw, off_e, list_e, b_inv, m, E);
    node_agg<true><<<nblk, 256, 0, stream>>>(m, off_n, list_n, d_inv, b1, out, N);

    // ---- layer 2: out = hconv(h, W2, b2) ----
    gemm128<<<gemm_blocks, 256, 0, stream>>>(out, W2, xw, N);
    edge_agg<<<eblk, 256, 0, stream>>>(xw, off_e, list_e, b_inv, m, E);
    node_agg<false><<<nblk, 256, 0, stream>>>(m, off_n, list_n, d_inv, b2, out, N);
}

// Round 6
// 410.838 us; speedup vs baseline: 3.9907x; 1.1092x over previous
//
#include <hip/hip_runtime.h>
#include <hip/hip_bf16.h>

// Problem constants (fixed by the reference)
#define D 128            // feature dim (in = hid = out = 128)
#define N_HEDGES 10000
#define SCAN_TILE 4096   // ints per block in the scan kernels (256 thr x 16)

// ---------------------------------------------------------------------------
// CSR build: count (+rank capture) -> 2-level scan -> XCD-partitioned fill.
// Round-5 lesson: scattered fill WRITE_SIZE is per-LINE (1.28M random writes
// x 64B = 86MB regardless of ushort vs int). Fix: partition destination
// segments into 8 contiguous ranges, one per XCD (blockIdx&7 ~ XCD round-
// robin), so each list line is written by a single XCD and stays in its L2.
// Ranks from count_k's atomicAdd return remove fill's atomics entirely.
// ---------------------------------------------------------------------------

__global__ void count_k(const int* __restrict__ row, const int* __restrict__ col,
                        int* __restrict__ cnt_n, int* __restrict__ cnt_e,
                        ushort* __restrict__ rank_n, ushort* __restrict__ rank_e,
                        int nnz) {
    int i = blockIdx.x * blockDim.x + threadIdx.x;
    if (i < nnz) {
        int pn = atomicAdd(&cnt_n[row[i]], 1);
        rank_n[i] = (ushort)pn;                  // rank < max node degree << 65536
        int pe = atomicAdd(&cnt_e[col[i]], 1);
        rank_e[i] = (ushort)pe;                  // rank < max edge degree << 65536
    }
}

// Level 1: per-block sums. grid = ceil(n/SCAN_TILE), block = 256.
// Round-2 lesson: single-block scan was 110us (1 CU, latency-bound).
__global__ __launch_bounds__(256) void scan_partial(const int* __restrict__ cnt,
                                                    int* __restrict__ psum, int n) {
    __shared__ int red[256];
    int t = threadIdx.x;
    int base = blockIdx.x * SCAN_TILE + t * 16;
    int s = 0;
#pragma unroll
    for (int j = 0; j < 4; ++j) {
        int idx = base + j * 4;
        if (idx + 3 < n) {
            int4 v = *(const int4*)(cnt + idx);
            s += v.x + v.y + v.z + v.w;
        } else {
            for (int k = 0; k < 4; ++k)
                if (idx + k < n) s += cnt[idx + k];
        }
    }
    red[t] = s;
    __syncthreads();
    for (int d = 128; d > 0; d >>= 1) {
        if (t < d) red[t] += red[t + d];
        __syncthreads();
    }
    if (t == 0) psum[blockIdx.x] = red[0];
}

// Level 2: per-block exclusive scan + base from partials (nP <= 16, read
// redundantly by every block). Writes off[0..n] and inv[0..n).
__global__ __launch_bounds__(256) void scan_final(const int* __restrict__ cnt,
                                                  const int* __restrict__ psum, int nP,
                                                  int* __restrict__ off,
                                                  float* __restrict__ inv, int n) {
    __shared__ int lsum[256];
    int t = threadIdx.x;
    int b = blockIdx.x;

    int block_base = 0, total = 0;
    for (int j = 0; j < nP; ++j) {
        int v = psum[j];
        if (j < b) block_base += v;
        total += v;
    }
    if (b == 0 && t == 0) off[n] = total;

    int base = b * SCAN_TILE + t * 16;
    int c[16];
#pragma unroll
    for (int j = 0; j < 4; ++j) {
        int idx = base + j * 4;
        if (idx + 3 < n) {
            int4 v = *(const int4*)(cnt + idx);
            c[j * 4 + 0] = v.x; c[j * 4 + 1] = v.y; c[j * 4 + 2] = v.z; c[j * 4 + 3] = v.w;
        } else {
            for (int k = 0; k < 4; ++k)
                c[j * 4 + k] = (idx + k < n) ? cnt[idx + k] : 0;
        }
    }
    int tot = 0;
#pragma unroll
    for (int j = 0; j < 16; ++j) tot += c[j];

    lsum[t] = tot;
    __syncthreads();
    for (int d = 1; d < 256; d <<= 1) {
        int v = (t >= d) ? lsum[t - d] : 0;
        __syncthreads();
        lsum[t] += v;
        __syncthreads();
    }
    int run = block_base + ((t == 0) ? 0 : lsum[t - 1]);

    int o[16];
    float iv[16];
#pragma unroll
    for (int j = 0; j < 16; ++j) {
        o[j] = run;
        iv[j] = (c[j] > 0) ? (1.0f / (float)c[j]) : 0.0f;
        run += c[j];
    }
#pragma unroll
    for (int j = 0; j < 4; ++j) {
        int idx = base + j * 4;
        if (idx + 3 < n) {
            *(int4*)(off + idx) = make_int4(o[j * 4], o[j * 4 + 1], o[j * 4 + 2], o[j * 4 + 3]);
            *(float4*)(inv + idx) = make_float4(iv[j * 4], iv[j * 4 + 1], iv[j * 4 + 2], iv[j * 4 + 3]);
        } else {
            for (int k = 0; k < 4; ++k)
                if (idx + k < n) { off[idx + k] = o[j * 4 + k]; inv[idx + k] = iv[j * 4 + k]; }
        }
    }
}

// XCD-partitioned scatter fill. grid = 8 * FILL_CHUNKS blocks.
// xcd = blockIdx&7; block scans incidence chunk blockIdx>>3, writing only
// destinations in its contiguous 1/8 of node / hyperedge index space.
#define FILL_CHUNKS 128
__global__ __launch_bounds__(256) void fill_part(const int* __restrict__ row,
                                                 const int* __restrict__ col,
                                                 const int* __restrict__ off_n,
                                                 const int* __restrict__ off_e,
                                                 const ushort* __restrict__ rank_n,
                                                 const ushort* __restrict__ rank_e,
                                                 ushort* __restrict__ list_n,
                                                 ushort* __restrict__ list_e,
                                                 int nnz, int N, int E) {
    int xcd = blockIdx.x & 7;
    int chunk = blockIdx.x >> 3;
    int csz = (nnz + FILL_CHUNKS - 1) / FILL_CHUNKS;
    int lo = chunk * csz;
    int hi = min(lo + csz, nnz);
    int nlo = (int)((long)N * xcd >> 3), nhi = (int)((long)N * (xcd + 1) >> 3);
    int elo = (int)((long)E * xcd >> 3), ehi = (int)((long)E * (xcd + 1) >> 3);
    for (int i = lo + threadIdx.x; i < hi; i += 256) {
        int r = row[i], c = col[i];
        if (r >= nlo && r < nhi) list_n[off_n[r] + rank_n[i]] = (ushort)c;
        if (c >= elo && c < ehi) list_e[off_e[c] + rank_e[i]] = (ushort)r;
    }
}

// ---------------------------------------------------------------------------
// fp32 GEMM: Y[M,128] = X[M,128] @ W[128,128]
// NOTE: k4 loop must NOT be fully unrolled — round-1 profile showed full unroll
// hoisted 1024 regs of LDS reads -> spill -> 1.06 GB scratch writes, 580 us.
// ---------------------------------------------------------------------------
__global__ __launch_bounds__(256, 2) void gemm128(const float* __restrict__ X,
                                                  const float* __restrict__ W,
                                                  float* __restrict__ Y, int M) {
    __shared__ float Wl[D * D];       // 64 KB
    __shared__ float Xl[32 * D];      // 16 KB
    int t = threadIdx.x;
    int block_row = blockIdx.x * 32;

    const float4* W4 = (const float4*)W;
    float4* Wl4 = (float4*)Wl;
#pragma unroll
    for (int i = 0; i < 16; ++i) Wl4[t + 256 * i] = W4[t + 256 * i];

    int rows = M - block_row; if (rows > 32) rows = 32;
#pragma unroll
    for (int i = 0; i < 4; ++i) {
        int idx = t + 256 * i;
        int r = idx >> 5, c4 = idx & 31;
        float4 v = make_float4(0.f, 0.f, 0.f, 0.f);
        if (r < rows) v = ((const float4*)(X + (size_t)(block_row + r) * D))[c4];
        ((float4*)Xl)[idx] = v;
    }
    __syncthreads();

    int cp = t & 63;
    int rg = t >> 6;                  // 0..3, 8 rows each
    float2 acc[8];
#pragma unroll
    for (int r = 0; r < 8; ++r) acc[r] = make_float2(0.f, 0.f);

    const float* xbase = Xl + (rg * 8) * D;
#pragma unroll 2
    for (int k4 = 0; k4 < 32; ++k4) {
        float2 wv0 = ((const float2*)(Wl + (k4 * 4 + 0) * D))[cp];
        float2 wv1 = ((const float2*)(Wl + (k4 * 4 + 1) * D))[cp];
        float2 wv2 = ((const float2*)(Wl + (k4 * 4 + 2) * D))[cp];
        float2 wv3 = ((const float2*)(Wl + (k4 * 4 + 3) * D))[cp];
#pragma unroll
        for (int r = 0; r < 8; ++r) {
            float4 xv = ((const float4*)(xbase + r * D))[k4];
            acc[r].x += xv.x * wv0.x; acc[r].y += xv.x * wv0.y;
            acc[r].x += xv.y * wv1.x; acc[r].y += xv.y * wv1.y;
            acc[r].x += xv.z * wv2.x; acc[r].y += xv.z * wv2.y;
            acc[r].x += xv.w * wv3.x; acc[r].y += xv.w * wv3.y;
        }
    }
#pragma unroll
    for (int r = 0; r < 8; ++r) {
        int row = block_row + rg * 8 + r;
        if (row < M) ((float2*)(Y + (size_t)row * D))[cp] = acc[r];
    }
}

// ---------------------------------------------------------------------------
// Segmented gather-sum, one wave per segment, 2 rows per iteration:
// lanes 0-31 take even incidences, lanes 32-63 odd; each half-wave reads a
// full 512B row as float4/lane.
// ---------------------------------------------------------------------------
__global__ __launch_bounds__(256) void edge_agg(const float* __restrict__ src,
                                                const int* __restrict__ offs,
                                                const ushort* __restrict__ list,
                                                const float* __restrict__ inv,
                                                float* __restrict__ dst, int nseg) {
    int w = (blockIdx.x * 256 + threadIdx.x) >> 6;
    int lane = threadIdx.x & 63;
    if (w >= nseg) return;
    int s = offs[w], e = offs[w + 1];
    int half = lane >> 5;
    int c4 = lane & 31;
    float4 acc = make_float4(0.f, 0.f, 0.f, 0.f);
    int i = s;
#pragma unroll 2
    for (; i + 2 <= e; i += 2) {
        int r = list[i + half];
        float4 v = ((const float4*)(src + (size_t)r * D))[c4];
        acc.x += v.x; acc.y += v.y; acc.z += v.z; acc.w += v.w;
    }
    if (i < e && half == 0) {
        int r = list[i];
        float4 v = ((const float4*)(src + (size_t)r * D))[c4];
        acc.x += v.x; acc.y += v.y; acc.z += v.z; acc.w += v.w;
    }
    acc.x += __shfl_xor(acc.x, 32);
    acc.y += __shfl_xor(acc.y, 32);
    acc.z += __shfl_xor(acc.z, 32);
    acc.w += __shfl_xor(acc.w, 32);
    if (half == 0) {
        float sc = inv[w];
        ((float4*)(dst + (size_t)w * D))[c4] =
            make_float4(acc.x * sc, acc.y * sc, acc.z * sc, acc.w * sc);
    }
}

template <bool RELU>
__global__ __launch_bounds__(256) void node_agg(const float* __restrict__ src,
                                                const int* __restrict__ offs,
                                                const ushort* __restrict__ list,
                                                const float* __restrict__ inv,
                                                const float* __restrict__ bias,
                                                float* __restrict__ dst, int nseg) {
    int w = (blockIdx.x * 256 + threadIdx.x) >> 6;
    int lane = threadIdx.x & 63;
    if (w >= nseg) return;
    int s = offs[w], e = offs[w + 1];
    int half = lane >> 5;
    int c4 = lane & 31;
    float4 acc = make_float4(0.f, 0.f, 0.f, 0.f);
    int i = s;
#pragma unroll 2
    for (; i + 2 <= e; i += 2) {
        int r = list[i + half];
        float4 v = ((const float4*)(src + (size_t)r * D))[c4];
        acc.x += v.x; acc.y += v.y; acc.z += v.z; acc.w += v.w;
    }
    if (i < e && half == 0) {
        int r = list[i];
        float4 v = ((const float4*)(src + (size_t)r * D))[c4];
        acc.x += v.x; acc.y += v.y; acc.z += v.z; acc.w += v.w;
    }
    acc.x += __shfl_xor(acc.x, 32);
    acc.y += __shfl_xor(acc.y, 32);
    acc.z += __shfl_xor(acc.z, 32);
    acc.w += __shfl_xor(acc.w, 32);
    if (half == 0) {
        float sc = inv[w];
        float4 bv = ((const float4*)bias)[c4];
        float ox = acc.x * sc + bv.x;
        float oy = acc.y * sc + bv.y;
        float oz = acc.z * sc + bv.z;
        float ow = acc.w * sc + bv.w;
        if (RELU) {
            ox = fmaxf(ox, 0.f); oy = fmaxf(oy, 0.f);
            oz = fmaxf(oz, 0.f); ow = fmaxf(ow, 0.f);
        }
        ((float4*)(dst + (size_t)w * D))[c4] = make_float4(ox, oy, oz, ow);
    }
}

// ---------------------------------------------------------------------------
// Launch
// ---------------------------------------------------------------------------
extern "C" void kernel_launch(void* const* d_in, const int* in_sizes, int n_in,
                              void* d_out, int out_size, void* d_ws, size_t ws_size,
                              hipStream_t stream) {
    const float* x  = (const float*)d_in[0];
    const int*   ei = (const int*)d_in[1];
    const float* W1 = (const float*)d_in[2];
    const float* b1 = (const float*)d_in[3];
    const float* W2 = (const float*)d_in[4];
    const float* b2 = (const float*)d_in[5];
    float* out = (float*)d_out;

    const int NNZ = in_sizes[1] / 2;
    const int N   = in_sizes[0] / D;       // 50000 nodes
    const int E   = N_HEDGES;              // 10000 hyperedges

    const int* row = ei;                   // node index per incidence
    const int* col = ei + NNZ;             // hyperedge index per incidence

    char* p = (char*)d_ws;
    auto alloc = [&](size_t bytes) {
        char* r = p;
        p += (bytes + 255) & ~(size_t)255;
        return r;
    };
    float* xw    = (float*)alloc(sizeof(float) * (size_t)N * D);  // 25.6 MB
    float* m     = (float*)alloc(sizeof(float) * (size_t)E * D);  // 5.12 MB
    int*   off_e = (int*)alloc(sizeof(int) * (E + 1));
    int*   off_n = (int*)alloc(sizeof(int) * (N + 1));
    float* b_inv = (float*)alloc(sizeof(float) * E);
    float* d_inv = (float*)alloc(sizeof(float) * N);
    int*   psum_e = (int*)alloc(sizeof(int) * 16);
    int*   psum_n = (int*)alloc(sizeof(int) * 16);
    ushort* rank_n = (ushort*)alloc(sizeof(ushort) * (size_t)NNZ);
    ushort* rank_e = (ushort*)alloc(sizeof(ushort) * (size_t)NNZ);
    ushort* list_e = (ushort*)alloc(sizeof(ushort) * (size_t)NNZ);
    ushort* list_n = (ushort*)alloc(sizeof(ushort) * (size_t)NNZ);
    char*  zstart = p;                                            // zero region start
    int*   cnt_e = (int*)alloc(sizeof(int) * E);
    int*   cnt_n = (int*)alloc(sizeof(int) * N);
    size_t zbytes = (size_t)(p - zstart);

    hipMemsetAsync(zstart, 0, zbytes, stream);

    int nnz_blocks = (NNZ + 255) / 256;
    int pE = (E + SCAN_TILE - 1) / SCAN_TILE;   // 3
    int pN = (N + SCAN_TILE - 1) / SCAN_TILE;   // 13

    count_k<<<nnz_blocks, 256, 0, stream>>>(row, col, cnt_n, cnt_e,
                                            rank_n, rank_e, NNZ);
    scan_partial<<<pE, 256, 0, stream>>>(cnt_e, psum_e, E);
    scan_partial<<<pN, 256, 0, stream>>>(cnt_n, psum_n, N);
    scan_final<<<pE, 256, 0, stream>>>(cnt_e, psum_e, pE, off_e, b_inv, E);
    scan_final<<<pN, 256, 0, stream>>>(cnt_n, psum_n, pN, off_n, d_inv, N);
    fill_part<<<8 * FILL_CHUNKS, 256, 0, stream>>>(row, col, off_n, off_e,
                                                   rank_n, rank_e,
                                                   list_n, list_e, NNZ, N, E);

    int gemm_blocks = (N + 31) / 32;
    int eblk = (E + 3) / 4;   // 4 waves per block
    int nblk = (N + 3) / 4;

    // ---- layer 1: h = relu(hconv(x, W1, b1)); h lives in d_out ----
    gemm128<<<gemm_blocks, 256, 0, stream>>>(x, W1, xw, N);
    edge_agg<<<eblk, 256, 0, stream>>>(xw, off_e, list_e, b_inv, m, E);
    node_agg<true><<<nblk, 256, 0, stream>>>(m, off_n, list_n, d_inv, b1, out, N);

    // ---- layer 2: out = hconv(h, W2, b2) ----
    gemm128<<<gemm_blocks, 256, 0, stream>>>(out, W2, xw, N);
    edge_agg<<<eblk, 256, 0, stream>>>(xw, off_e, list_e, b_inv, m, E);
    node_agg<false><<<nblk, 256, 0, stream>>>(m, off_n, list_n, d_inv, b2, out, N);
}